// Round 4
// baseline (157.575 us; speedup 1.0000x reference)
//
#include <hip/hip_runtime.h>
#include <math.h>

#define NLEAVES 8192
constexpr int NT    = 512;          // threads/block (8 waves)
constexpr int NSLOT = 16;           // 32-lane q-slots

// ---- LDS layout (floats) ----
// E4[lr*32 + (lp ^ (lr&7))] = exp(trans[lp][l][4*r4..+3]), lr = l*8+r4
constexpr int ROWP  = 36;
constexpr int PARTP = 33;
constexpr int OFF_E    = 0;
constexpr int OFF_BUF  = 32768;                 // 128 KB of E
constexpr int OFF_P0   = OFF_BUF + 32 * ROWP;
constexpr int OFF_P1   = OFF_P0 + NSLOT * PARTP;
constexpr int OFF_R    = OFF_P1 + NSLOT * PARTP;
constexpr int OFF_FLAG = OFF_R + 64;
constexpr int SMEM_F32 = OFF_FLAG + 4;
constexpr size_t SMEM_BYTES = (size_t)SMEM_F32 * 4;   // ~137 KB -> 1 block/CU

// Reduce IN consecutive score rows (rows blk*IN ..) through LEVELS levels in
// LDS; root row -> outp[blk*32+lp]. NTOT = global node count at input level.
template<int IN, int LEVELS>
__device__ __forceinline__
void subtree(const float* __restrict__ in, float* __restrict__ outp,
             const float* __restrict__ iem, int NTOT, int blk,
             float* sm, int tid, int lp, int q) {
    float* Ef  = sm + OFF_E;
    float* buf = sm + OFF_BUF;
    float* p0  = sm + OFF_P0;
    float* p1  = sm + OFF_P1;
    float* rm  = sm + OFF_R;

    // prepass: rows -> exp(v - rowmax); rowmax -> rm (parity 0)
    for (int rr = q; rr < IN; rr += NSLOT) {
        float v = in[(blk * IN + rr) * 32 + lp];
        float gm = v;
        #pragma unroll
        for (int kk = 16; kk >= 1; kk >>= 1) gm = fmaxf(gm, __shfl_xor(gm, kk));
        buf[rr * ROWP + lp] = expf(v - gm);
        if (lp == 0) rm[rr] = gm;
    }
    __syncthreads();

    #pragma unroll
    for (int k = 1; k <= LEVELS; ++k) {
        const int m      = IN >> k;
        const int npairs = (m >= 2) ? (m >> 1) : 1;
        const int S      = NSLOT / npairs;            // slots per pair
        const int llen   = 32 / S;                    // l-values per slot
        const int lgnp   = (npairs == 8) ? 3 : (npairs == 4) ? 2
                         : (npairs == 2) ? 1 : 0;
        const int tile = q & (npairs - 1);
        const int seg  = q >> lgnp;
        const float* rprev = rm + ((k & 1) ? 0 : 32);
        float*       rnext = rm + ((k & 1) ? 32 : 0);
        const int ra0 = 4 * tile, rb0 = 4 * tile + 1;
        const int ra1 = 4 * tile + 2, rb1 = 4 * tile + 3;   // stale-but-finite when m==1

        float4 b0[8], b1[8];
        {
            const float4* pb0 = (const float4*)(buf + rb0 * ROWP);
            const float4* pb1 = (const float4*)(buf + rb1 * ROWP);
            #pragma unroll
            for (int r = 0; r < 8; ++r) { b0[r] = pb0[r]; b1[r] = pb1[r]; }
        }
        float s0 = 0.f, s1v = 0.f;
        #pragma unroll
        for (int li = 0; li < llen; ++li) {
            const int l = seg * llen + li;
            const float a0 = buf[ra0 * ROWP + l];
            const float a1 = buf[ra1 * ROWP + l];
            const float4* E4 = (const float4*)Ef + l * 256;
            float u0 = 0.f, u1 = 0.f;
            #pragma unroll
            for (int r4 = 0; r4 < 8; ++r4) {
                const float4 e = E4[r4 * 32 + (lp ^ r4)];
                u0 = fmaf(b0[r4].x, e.x, u0); u0 = fmaf(b0[r4].y, e.y, u0);
                u0 = fmaf(b0[r4].z, e.z, u0); u0 = fmaf(b0[r4].w, e.w, u0);
                u1 = fmaf(b1[r4].x, e.x, u1); u1 = fmaf(b1[r4].y, e.y, u1);
                u1 = fmaf(b1[r4].z, e.z, u1); u1 = fmaf(b1[r4].w, e.w, u1);
            }
            s0  = fmaf(a0, u0, s0);
            s1v = fmaf(a1, u1, s1v);
        }
        p0[q * PARTP + lp] = s0;
        p1[q * PARTP + lp] = s1v;
        __syncthreads();

        if (tid < m * 32) {
            const int node = q;
            const int tl   = node >> 1;
            const float* pp = (node & 1) ? p1 : p0;
            float acc = 0.f;
            #pragma unroll
            for (int s = 0; s < S; ++s) acc += pp[(s * npairs + tl) * PARTP + lp];
            const float em = iem[(NLEAVES - 2 * (NTOT >> k) + blk * m + node) * 32 + lp];
            const float raw = em + rprev[2 * node] + rprev[2 * node + 1] + logf(acc);
            if (k == LEVELS) {
                outp[blk * 32 + lp] = raw;            // m==1, node==0
            } else {
                float gm = raw;
                #pragma unroll
                for (int kk = 16; kk >= 1; kk >>= 1) gm = fmaxf(gm, __shfl_xor(gm, kk));
                buf[node * ROWP + lp] = expf(raw - gm);   // in-place: phase2 reads only p/rm
                if (lp == 0) rnext[node] = gm;
            }
        }
        __syncthreads();
    }
}

// Single fused dispatch: stage1 (256 blocks) -> group arrival -> stage2
// (8 last-arriver blocks) -> final arrival -> stage3 (1 block). No spinning:
// non-last blocks simply exit, so no co-residency / dispatch-order assumption.
__global__ __launch_bounds__(NT, 1)
void fused_tree(const float* __restrict__ leaf, const float* __restrict__ iem,
                const float* __restrict__ trans, float* __restrict__ s1,
                float* __restrict__ s2, float* __restrict__ out,
                int* __restrict__ cnt) {
    extern __shared__ __align__(16) float sm[];
    const int tid = threadIdx.x;
    const int lp  = tid & 31;
    const int q   = tid >> 5;
    const int bid = blockIdx.x;
    int* flag = (int*)(sm + OFF_FLAG);

    // build exp(T), block-rotated first touch
    {
        const float4* t4 = (const float4*)trans;
        float4* E4 = (float4*)(sm + OFF_E);
        #pragma unroll
        for (int it = 0; it < 16; ++it) {
            const int idx = (tid + it * NT + bid * 32) & 8191;
            const int lp_s = idx >> 8, lr = idx & 255;
            float4 v = t4[idx];
            float4 e;
            e.x = expf(v.x); e.y = expf(v.y); e.z = expf(v.z); e.w = expf(v.w);
            E4[lr * 32 + (lp_s ^ (lr & 7))] = e;
        }
    }
    // stage 1: 32 leaves -> 1 root row in s1  (subtree starts with the needed barrier's producer side; its internal __syncthreads covers the E build)
    subtree<32, 5>(leaf, s1, iem, 8192, bid, sm, tid, lp, q);

    // group arrival (release)
    if (tid == 0) {
        __threadfence();                                   // wb: s1 row visible device-wide
        *flag = (atomicAdd(&cnt[bid >> 5], 1) == 31) ? 1 : 0;
    }
    __syncthreads();
    if (!*flag) return;
    if (tid == 0) __threadfence();                         // acquire: invalidate stale L1/L2
    __syncthreads();

    // stage 2: 32 group roots -> 1 row in s2 (E still in LDS)
    const int g = bid >> 5;
    subtree<32, 5>(s1, s2, iem, 256, g, sm, tid, lp, q);

    // final arrival
    if (tid == 0) {
        __threadfence();
        *flag = (atomicAdd(&cnt[8], 1) == 7) ? 1 : 0;
    }
    __syncthreads();
    if (!*flag) return;
    if (tid == 0) __threadfence();
    __syncthreads();

    // stage 3: 8 rows -> final root
    subtree<8, 3>(s2, out, iem, 8, 0, sm, tid, lp, q);
}

extern "C" void kernel_launch(void* const* d_in, const int* in_sizes, int n_in,
                              void* d_out, int out_size, void* d_ws, size_t ws_size,
                              hipStream_t stream) {
    const float* leaf  = (const float*)d_in[0];   // [8192,32]
    const float* iem   = (const float*)d_in[1];   // [8191,32]
    const float* trans = (const float*)d_in[2];   // [32,32,32]
    float* out = (float*)d_out;                   // [32]

    float* s1 = (float*)d_ws;                     // 256*32 f32
    float* s2 = s1 + 256 * 32;                    // 8*32 f32
    int*  cnt = (int*)(s2 + 8 * 32);              // 9 ints

    (void)hipMemsetAsync(cnt, 0, 9 * sizeof(int), stream);
    (void)hipFuncSetAttribute((const void*)fused_tree,
                              hipFuncAttributeMaxDynamicSharedMemorySize,
                              (int)SMEM_BYTES);
    fused_tree<<<256, NT, SMEM_BYTES, stream>>>(leaf, iem, trans, s1, s2, out, cnt);
}

// Round 5
// 46.543 us; speedup vs baseline: 3.3856x; 3.3856x over previous
//
#include <hip/hip_runtime.h>
#include <math.h>

#define NLEAVES 8192
constexpr int NT    = 512;          // threads/block (8 waves)
constexpr int NSLOT = 16;           // 32-lane q-slots

// ---- LDS layout (floats) ----
// E4[lr*32 + (lp ^ (lr&7))] = exp(trans[lp][l][4*r4..+3]), lr = l*8+r4
constexpr int ROWP  = 36;                       // 144B rows, 16B-aligned
constexpr int PARTP = 33;
constexpr int OFF_E    = 0;
constexpr int OFF_BUF  = 32768;                 // 128 KB of E
constexpr int OFF_P0   = OFF_BUF + 32 * ROWP;
constexpr int OFF_P1   = OFF_P0 + NSLOT * PARTP;
constexpr int OFF_P2   = OFF_P1 + NSLOT * PARTP;
constexpr int OFF_P3   = OFF_P2 + NSLOT * PARTP;
constexpr int OFF_R    = OFF_P3 + NSLOT * PARTP;
constexpr int OFF_FLAG = OFF_R + 64;
constexpr int SMEM_F32 = OFF_FLAG + 4;
constexpr size_t SMEM_BYTES = (size_t)SMEM_F32 * 4;   // ~141 KB -> 1 block/CU

__device__ __forceinline__ void build_E(const float* __restrict__ trans,
                                        float* sm, int tid, int bid) {
    const float4* t4 = (const float4*)trans;    // t4[lp_s*256 + lr]
    float4* E4 = (float4*)(sm + OFF_E);
    #pragma unroll
    for (int it = 0; it < 16; ++it) {
        const int idx = (tid + it * NT + bid * 32) & 8191;  // block-rotated
        const int lp_s = idx >> 8, lr = idx & 255;
        float4 v = t4[idx];
        float4 e;
        e.x = expf(v.x); e.y = expf(v.y); e.z = expf(v.z); e.w = expf(v.w);
        E4[lr * 32 + (lp_s ^ (lr & 7))] = e;
    }
}

// Reduce IN consecutive score rows (rows blk*IN ..) through LEVELS levels in
// LDS; root row -> outp[blk*32+lp]. NTOT = global node count at input level.
// Levels with m>=4 nodes: quad-sharing (4 nodes per E read). m<=2: pair path.
template<int IN, int LEVELS>
__device__ __forceinline__
void subtree(const float* __restrict__ in, float* __restrict__ outp,
             const float* __restrict__ iem, int NTOT, int blk,
             float* sm, int tid, int lp, int q) {
    float* Ef  = sm + OFF_E;
    float* buf = sm + OFF_BUF;
    float* p0  = sm + OFF_P0;
    float* p1  = sm + OFF_P1;
    float* p2  = sm + OFF_P2;
    float* p3  = sm + OFF_P3;
    float* rm  = sm + OFF_R;

    // prepass: rows -> exp(v - rowmax); rowmax -> rm (parity 0)
    for (int rr = q; rr < IN; rr += NSLOT) {
        float v = in[(blk * IN + rr) * 32 + lp];
        float gm = v;
        #pragma unroll
        for (int kk = 16; kk >= 1; kk >>= 1) gm = fmaxf(gm, __shfl_xor(gm, kk));
        buf[rr * ROWP + lp] = expf(v - gm);
        if (lp == 0) rm[rr] = gm;
    }
    __syncthreads();

    #pragma unroll
    for (int k = 1; k <= LEVELS; ++k) {
        const int m = IN >> k;                    // nodes this level
        const float* rprev = rm + ((k & 1) ? 0 : 32);
        float*       rnext = rm + ((k & 1) ? 32 : 0);
        int S_acc;                                // segments to sum in phase 2

        if (m >= 4) {
            // ---- quad phase 1: 4 nodes share each E read ----
            const int nq   = m >> 2;
            const int S    = NSLOT / nq;
            const int llen = 32 / S;
            const int lgnq = (nq == 4) ? 2 : (nq == 2) ? 1 : 0;
            const int quad = q & (nq - 1);
            const int seg  = q >> lgnq;
            const int base = 8 * quad;
            S_acc = S;

            float4 b0[8], b1[8], b2[8], b3[8];
            {
                const float4* pb0 = (const float4*)(buf + (base + 1) * ROWP);
                const float4* pb1 = (const float4*)(buf + (base + 3) * ROWP);
                const float4* pb2 = (const float4*)(buf + (base + 5) * ROWP);
                const float4* pb3 = (const float4*)(buf + (base + 7) * ROWP);
                #pragma unroll
                for (int r = 0; r < 8; ++r) {
                    b0[r] = pb0[r]; b1[r] = pb1[r];
                    b2[r] = pb2[r]; b3[r] = pb3[r];
                }
            }
            float s0 = 0.f, s1v = 0.f, s2v = 0.f, s3v = 0.f;
            #pragma unroll
            for (int li = 0; li < llen; ++li) {
                const int l = seg * llen + li;
                const float a0 = buf[(base + 0) * ROWP + l];
                const float a1 = buf[(base + 2) * ROWP + l];
                const float a2 = buf[(base + 4) * ROWP + l];
                const float a3 = buf[(base + 6) * ROWP + l];
                const float4* E4p = (const float4*)Ef + l * 256;
                float u0 = 0.f, u1 = 0.f, u2 = 0.f, u3 = 0.f;
                #pragma unroll
                for (int r4 = 0; r4 < 8; ++r4) {
                    const float4 e = E4p[r4 * 32 + (lp ^ r4)];
                    u0 = fmaf(b0[r4].x, e.x, u0); u0 = fmaf(b0[r4].y, e.y, u0);
                    u0 = fmaf(b0[r4].z, e.z, u0); u0 = fmaf(b0[r4].w, e.w, u0);
                    u1 = fmaf(b1[r4].x, e.x, u1); u1 = fmaf(b1[r4].y, e.y, u1);
                    u1 = fmaf(b1[r4].z, e.z, u1); u1 = fmaf(b1[r4].w, e.w, u1);
                    u2 = fmaf(b2[r4].x, e.x, u2); u2 = fmaf(b2[r4].y, e.y, u2);
                    u2 = fmaf(b2[r4].z, e.z, u2); u2 = fmaf(b2[r4].w, e.w, u2);
                    u3 = fmaf(b3[r4].x, e.x, u3); u3 = fmaf(b3[r4].y, e.y, u3);
                    u3 = fmaf(b3[r4].z, e.z, u3); u3 = fmaf(b3[r4].w, e.w, u3);
                }
                s0  = fmaf(a0, u0, s0);
                s1v = fmaf(a1, u1, s1v);
                s2v = fmaf(a2, u2, s2v);
                s3v = fmaf(a3, u3, s3v);
            }
            p0[q * PARTP + lp] = s0;
            p1[q * PARTP + lp] = s1v;
            p2[q * PARTP + lp] = s2v;
            p3[q * PARTP + lp] = s3v;
        } else {
            // ---- pair phase 1 (m <= 2) ----
            const int llen = 2;                   // S = 16
            const int seg  = q;
            S_acc = 16;
            float4 b0[8], b1[8];
            {
                const float4* pb0 = (const float4*)(buf + 1 * ROWP);
                const float4* pb1 = (const float4*)(buf + 3 * ROWP);
                #pragma unroll
                for (int r = 0; r < 8; ++r) { b0[r] = pb0[r]; b1[r] = pb1[r]; }
            }
            float s0 = 0.f, s1v = 0.f;
            #pragma unroll
            for (int li = 0; li < llen; ++li) {
                const int l = seg * llen + li;
                const float a0 = buf[0 * ROWP + l];
                const float a1 = buf[2 * ROWP + l];
                const float4* E4p = (const float4*)Ef + l * 256;
                float u0 = 0.f, u1 = 0.f;
                #pragma unroll
                for (int r4 = 0; r4 < 8; ++r4) {
                    const float4 e = E4p[r4 * 32 + (lp ^ r4)];
                    u0 = fmaf(b0[r4].x, e.x, u0); u0 = fmaf(b0[r4].y, e.y, u0);
                    u0 = fmaf(b0[r4].z, e.z, u0); u0 = fmaf(b0[r4].w, e.w, u0);
                    u1 = fmaf(b1[r4].x, e.x, u1); u1 = fmaf(b1[r4].y, e.y, u1);
                    u1 = fmaf(b1[r4].z, e.z, u1); u1 = fmaf(b1[r4].w, e.w, u1);
                }
                s0  = fmaf(a0, u0, s0);
                s1v = fmaf(a1, u1, s1v);
            }
            p0[q * PARTP + lp] = s0;
            p1[q * PARTP + lp] = s1v;
        }
        __syncthreads();

        // ---- phase 2: combine partials, add emissions, log ----
        if (tid < m * 32) {
            const int node = q;
            float acc = 0.f;
            if (m >= 4) {
                const int nq = m >> 2;
                const int j  = node & 3;
                const int qd = node >> 2;
                const float* pp = (j == 0) ? p0 : (j == 1) ? p1 : (j == 2) ? p2 : p3;
                #pragma unroll
                for (int s = 0; s < 16; ++s) {
                    if (s < S_acc) acc += pp[(s * nq + qd) * PARTP + lp];
                }
            } else {
                const float* pp = (node & 1) ? p1 : p0;
                #pragma unroll
                for (int s = 0; s < 16; ++s) acc += pp[s * PARTP + lp];
            }
            const float em = iem[(NLEAVES - 2 * (NTOT >> k) + blk * m + node) * 32 + lp];
            const float raw = em + rprev[2 * node] + rprev[2 * node + 1] + logf(acc);
            if (k == LEVELS) {
                outp[blk * 32 + lp] = raw;        // m==1, node==0
            } else {
                float gm = raw;
                #pragma unroll
                for (int kk = 16; kk >= 1; kk >>= 1) gm = fmaxf(gm, __shfl_xor(gm, kk));
                buf[node * ROWP + lp] = expf(raw - gm);   // in-place: phase2 reads only p/rm
                if (lp == 0) rnext[node] = gm;
            }
        }
        __syncthreads();
    }
}

// K1: 256 blocks, 32 leaves each -> s1[256 rows]
__global__ __launch_bounds__(NT, 1)
void k1_kernel(const float* __restrict__ leaf, float* __restrict__ s1,
               const float* __restrict__ iem, const float* __restrict__ trans) {
    extern __shared__ __align__(16) float sm[];
    const int tid = threadIdx.x, lp = tid & 31, q = tid >> 5;
    build_E(trans, sm, tid, blockIdx.x);
    subtree<32, 5>(leaf, s1, iem, 8192, blockIdx.x, sm, tid, lp, q);
}

// Tail: 8 blocks reduce s1(256 rows) -> s2(8 rows); last arriver does 8 -> out.
__global__ __launch_bounds__(NT, 1)
void tail_kernel(const float* __restrict__ s1, float* __restrict__ s2,
                 float* __restrict__ out, const float* __restrict__ iem,
                 const float* __restrict__ trans, int* __restrict__ cnt) {
    extern __shared__ __align__(16) float sm[];
    const int tid = threadIdx.x, lp = tid & 31, q = tid >> 5;
    int* flag = (int*)(sm + OFF_FLAG);
    build_E(trans, sm, tid, blockIdx.x);
    subtree<32, 5>(s1, s2, iem, 256, blockIdx.x, sm, tid, lp, q);

    if (tid == 0) {
        __threadfence();                              // release s2 row device-wide
        *flag = (atomicAdd(cnt, 1) == 7) ? 1 : 0;
    }
    __syncthreads();
    if (!*flag) return;
    if (tid == 0) __threadfence();                    // acquire
    __syncthreads();

    subtree<8, 3>(s2, out, iem, 8, 0, sm, tid, lp, q);
}

extern "C" void kernel_launch(void* const* d_in, const int* in_sizes, int n_in,
                              void* d_out, int out_size, void* d_ws, size_t ws_size,
                              hipStream_t stream) {
    const float* leaf  = (const float*)d_in[0];   // [8192,32]
    const float* iem   = (const float*)d_in[1];   // [8191,32]
    const float* trans = (const float*)d_in[2];   // [32,32,32]
    float* out = (float*)d_out;                   // [32]

    float* s1 = (float*)d_ws;                     // 256*32 f32
    float* s2 = s1 + 256 * 32;                    // 8*32 f32
    int*  cnt = (int*)(s2 + 8 * 32);              // 1 int

    (void)hipMemsetAsync(cnt, 0, sizeof(int), stream);
    (void)hipFuncSetAttribute((const void*)k1_kernel,
                              hipFuncAttributeMaxDynamicSharedMemorySize,
                              (int)SMEM_BYTES);
    (void)hipFuncSetAttribute((const void*)tail_kernel,
                              hipFuncAttributeMaxDynamicSharedMemorySize,
                              (int)SMEM_BYTES);

    k1_kernel<<<256, NT, SMEM_BYTES, stream>>>(leaf, s1, iem, trans);
    tail_kernel<<<8, NT, SMEM_BYTES, stream>>>(s1, s2, out, iem, trans, cnt);
}

// Round 8
// 41.427 us; speedup vs baseline: 3.8037x; 1.1235x over previous
//
#include <hip/hip_runtime.h>
#include <math.h>

#define NLEAVES 8192
constexpr int NT    = 512;          // threads/block (8 waves)
constexpr int NSLOT = 16;           // 32-lane q-slots

// ---- LDS layout (floats) ----
// E4[lr*32 + (lp ^ (lr&7))] = exp(trans[lp][l][4*r4..+3]), lr = l*8+r4
constexpr int ROWP  = 36;                       // 144B rows, 16B-aligned
constexpr int PARTP = 33;
constexpr int OFF_E    = 0;
constexpr int OFF_BUF  = 32768;                 // 128 KB of E
constexpr int OFF_P0   = OFF_BUF + 32 * ROWP;
constexpr int OFF_P1   = OFF_P0 + NSLOT * PARTP;
constexpr int OFF_P2   = OFF_P1 + NSLOT * PARTP;
constexpr int OFF_P3   = OFF_P2 + NSLOT * PARTP;
constexpr int OFF_R    = OFF_P3 + NSLOT * PARTP;
constexpr int OFF_FLAG = OFF_R + 64;
constexpr int SMEM_F32 = OFF_FLAG + 4;
constexpr size_t SMEM_BYTES = (size_t)SMEM_F32 * 4;   // ~141 KB -> 1 block/CU

__device__ __forceinline__ void build_E(const float* __restrict__ trans,
                                        float* sm, int tid, int bid) {
    const float4* t4 = (const float4*)trans;    // t4[lp_s*256 + lr]
    float4* E4 = (float4*)(sm + OFF_E);
    #pragma unroll
    for (int it = 0; it < 16; ++it) {
        const int idx = (tid + it * NT + bid * 32) & 8191;  // block-rotated
        const int lp_s = idx >> 8, lr = idx & 255;
        float4 v = t4[idx];
        float4 e;
        e.x = expf(v.x); e.y = expf(v.y); e.z = expf(v.z); e.w = expf(v.w);
        E4[lr * 32 + (lp_s ^ (lr & 7))] = e;
    }
}

// Reduce IN consecutive score rows (rows blk*IN ..) through LEVELS levels in
// LDS; root row -> outp[blk*32+lp]. NTOT = global node count at input level.
// Levels with m>=4 nodes: quad-sharing (4 nodes per E read). m<=2: pair path.
template<int IN, int LEVELS>
__device__ __forceinline__
void subtree(const float* __restrict__ in, float* __restrict__ outp,
             const float* __restrict__ iem, int NTOT, int blk,
             float* sm, int tid, int lp, int q) {
    float* Ef  = sm + OFF_E;
    float* buf = sm + OFF_BUF;
    float* p0  = sm + OFF_P0;
    float* p1  = sm + OFF_P1;
    float* p2  = sm + OFF_P2;
    float* p3  = sm + OFF_P3;
    float* rm  = sm + OFF_R;

    // prepass: rows -> exp(v - rowmax); rowmax -> rm (parity 0)
    for (int rr = q; rr < IN; rr += NSLOT) {
        float v = in[(blk * IN + rr) * 32 + lp];
        float gm = v;
        #pragma unroll
        for (int kk = 16; kk >= 1; kk >>= 1) gm = fmaxf(gm, __shfl_xor(gm, kk));
        buf[rr * ROWP + lp] = expf(v - gm);
        if (lp == 0) rm[rr] = gm;
    }
    __syncthreads();

    #pragma unroll
    for (int k = 1; k <= LEVELS; ++k) {
        const int m = IN >> k;                    // nodes this level
        const float* rprev = rm + ((k & 1) ? 0 : 32);
        float*       rnext = rm + ((k & 1) ? 32 : 0);
        int S_acc;                                // segments to sum in phase 2

        if (m >= 4) {
            // ---- quad phase 1: 4 nodes share each E read ----
            const int nq   = m >> 2;
            const int S    = NSLOT / nq;
            const int llen = 32 / S;
            const int lgnq = (nq == 4) ? 2 : (nq == 2) ? 1 : 0;
            const int quad = q & (nq - 1);
            const int seg  = q >> lgnq;
            const int base = 8 * quad;
            S_acc = S;

            float4 b0[8], b1[8], b2[8], b3[8];
            {
                const float4* pb0 = (const float4*)(buf + (base + 1) * ROWP);
                const float4* pb1 = (const float4*)(buf + (base + 3) * ROWP);
                const float4* pb2 = (const float4*)(buf + (base + 5) * ROWP);
                const float4* pb3 = (const float4*)(buf + (base + 7) * ROWP);
                #pragma unroll
                for (int r = 0; r < 8; ++r) {
                    b0[r] = pb0[r]; b1[r] = pb1[r];
                    b2[r] = pb2[r]; b3[r] = pb3[r];
                }
            }
            float s0 = 0.f, s1v = 0.f, s2v = 0.f, s3v = 0.f;
            #pragma unroll
            for (int li = 0; li < llen; ++li) {
                const int l = seg * llen + li;
                const float a0 = buf[(base + 0) * ROWP + l];
                const float a1 = buf[(base + 2) * ROWP + l];
                const float a2 = buf[(base + 4) * ROWP + l];
                const float a3 = buf[(base + 6) * ROWP + l];
                const float4* E4p = (const float4*)Ef + l * 256;
                float u0 = 0.f, u1 = 0.f, u2 = 0.f, u3 = 0.f;
                #pragma unroll
                for (int r4 = 0; r4 < 8; ++r4) {
                    const float4 e = E4p[r4 * 32 + (lp ^ r4)];
                    u0 = fmaf(b0[r4].x, e.x, u0); u0 = fmaf(b0[r4].y, e.y, u0);
                    u0 = fmaf(b0[r4].z, e.z, u0); u0 = fmaf(b0[r4].w, e.w, u0);
                    u1 = fmaf(b1[r4].x, e.x, u1); u1 = fmaf(b1[r4].y, e.y, u1);
                    u1 = fmaf(b1[r4].z, e.z, u1); u1 = fmaf(b1[r4].w, e.w, u1);
                    u2 = fmaf(b2[r4].x, e.x, u2); u2 = fmaf(b2[r4].y, e.y, u2);
                    u2 = fmaf(b2[r4].z, e.z, u2); u2 = fmaf(b2[r4].w, e.w, u2);
                    u3 = fmaf(b3[r4].x, e.x, u3); u3 = fmaf(b3[r4].y, e.y, u3);
                    u3 = fmaf(b3[r4].z, e.z, u3); u3 = fmaf(b3[r4].w, e.w, u3);
                }
                s0  = fmaf(a0, u0, s0);
                s1v = fmaf(a1, u1, s1v);
                s2v = fmaf(a2, u2, s2v);
                s3v = fmaf(a3, u3, s3v);
            }
            p0[q * PARTP + lp] = s0;
            p1[q * PARTP + lp] = s1v;
            p2[q * PARTP + lp] = s2v;
            p3[q * PARTP + lp] = s3v;
        } else {
            // ---- pair phase 1 (m <= 2) ----
            const int llen = 2;                   // S = 16
            const int seg  = q;
            S_acc = 16;
            float4 b0[8], b1[8];
            {
                const float4* pb0 = (const float4*)(buf + 1 * ROWP);
                const float4* pb1 = (const float4*)(buf + 3 * ROWP);
                #pragma unroll
                for (int r = 0; r < 8; ++r) { b0[r] = pb0[r]; b1[r] = pb1[r]; }
            }
            float s0 = 0.f, s1v = 0.f;
            #pragma unroll
            for (int li = 0; li < llen; ++li) {
                const int l = seg * llen + li;
                const float a0 = buf[0 * ROWP + l];
                const float a1 = buf[2 * ROWP + l];
                const float4* E4p = (const float4*)Ef + l * 256;
                float u0 = 0.f, u1 = 0.f;
                #pragma unroll
                for (int r4 = 0; r4 < 8; ++r4) {
                    const float4 e = E4p[r4 * 32 + (lp ^ r4)];
                    u0 = fmaf(b0[r4].x, e.x, u0); u0 = fmaf(b0[r4].y, e.y, u0);
                    u0 = fmaf(b0[r4].z, e.z, u0); u0 = fmaf(b0[r4].w, e.w, u0);
                    u1 = fmaf(b1[r4].x, e.x, u1); u1 = fmaf(b1[r4].y, e.y, u1);
                    u1 = fmaf(b1[r4].z, e.z, u1); u1 = fmaf(b1[r4].w, e.w, u1);
                }
                s0  = fmaf(a0, u0, s0);
                s1v = fmaf(a1, u1, s1v);
            }
            p0[q * PARTP + lp] = s0;
            p1[q * PARTP + lp] = s1v;
        }
        __syncthreads();

        // ---- phase 2: combine partials, add emissions, log ----
        if (tid < m * 32) {
            const int node = q;
            float acc = 0.f;
            if (m >= 4) {
                const int nq = m >> 2;
                const int j  = node & 3;
                const int qd = node >> 2;
                const float* pp = (j == 0) ? p0 : (j == 1) ? p1 : (j == 2) ? p2 : p3;
                #pragma unroll
                for (int s = 0; s < 16; ++s) {
                    if (s < S_acc) acc += pp[(s * nq + qd) * PARTP + lp];
                }
            } else {
                const float* pp = (node & 1) ? p1 : p0;
                #pragma unroll
                for (int s = 0; s < 16; ++s) acc += pp[s * PARTP + lp];
            }
            const float em = iem[(NLEAVES - 2 * (NTOT >> k) + blk * m + node) * 32 + lp];
            const float raw = em + rprev[2 * node] + rprev[2 * node + 1] + logf(acc);
            if (k == LEVELS) {
                outp[blk * 32 + lp] = raw;        // m==1, node==0
            } else {
                float gm = raw;
                #pragma unroll
                for (int kk = 16; kk >= 1; kk >>= 1) gm = fmaxf(gm, __shfl_xor(gm, kk));
                buf[node * ROWP + lp] = expf(raw - gm);   // in-place: phase2 reads only p/rm
                if (lp == 0) rnext[node] = gm;
            }
        }
        __syncthreads();
    }
}

// K1: 256 blocks, 32 leaves each -> s1[256 rows]. The k1->tail kernel
// boundary is the (only) system-level flush we rely on for the 256-producer
// s1 handoff -- R6/R7 proved the intra-kernel 256-block version is racy.
__global__ __launch_bounds__(NT, 1)
void k1_kernel(const float* __restrict__ leaf, float* __restrict__ s1,
               const float* __restrict__ iem, const float* __restrict__ trans) {
    extern __shared__ __align__(16) float sm[];
    const int tid = threadIdx.x, lp = tid & 31, q = tid >> 5;
    build_E(trans, sm, tid, blockIdx.x);
    subtree<32, 5>(leaf, s1, iem, 8192, blockIdx.x, sm, tid, lp, q);
}

// Tail: 8 blocks reduce s1(256 rows) -> s2(8 rows); last arriver does 8->out.
// Persistent counter, never reset: among any 8 consecutive fetch_add returns
// exactly one satisfies (old&7)==7 (wrap-safe, works from the 0xAA poison),
// so no memset graph node is needed. Fence pattern is R5's verbatim.
__global__ __launch_bounds__(NT, 1)
void tail_kernel(const float* __restrict__ s1, float* __restrict__ s2,
                 float* __restrict__ out, const float* __restrict__ iem,
                 const float* __restrict__ trans, unsigned* __restrict__ cnt) {
    extern __shared__ __align__(16) float sm[];
    const int tid = threadIdx.x, lp = tid & 31, q = tid >> 5;
    int* flag = (int*)(sm + OFF_FLAG);
    build_E(trans, sm, tid, blockIdx.x);
    subtree<32, 5>(s1, s2, iem, 256, blockIdx.x, sm, tid, lp, q);

    if (tid == 0) {
        __threadfence();                              // release s2 row device-wide
        unsigned old = atomicAdd(cnt, 1u);
        *flag = ((old & 7u) == 7u) ? 1 : 0;
    }
    __syncthreads();
    if (!*flag) return;
    if (tid == 0) __threadfence();                    // acquire
    __syncthreads();

    subtree<8, 3>(s2, out, iem, 8, 0, sm, tid, lp, q);
}

extern "C" void kernel_launch(void* const* d_in, const int* in_sizes, int n_in,
                              void* d_out, int out_size, void* d_ws, size_t ws_size,
                              hipStream_t stream) {
    const float* leaf  = (const float*)d_in[0];   // [8192,32]
    const float* iem   = (const float*)d_in[1];   // [8191,32]
    const float* trans = (const float*)d_in[2];   // [32,32,32]
    float* out = (float*)d_out;                   // [32]

    float* s1     = (float*)d_ws;                 // 256*32 f32
    float* s2     = s1 + 256 * 32;                // 8*32 f32
    unsigned* cnt = (unsigned*)(s2 + 8 * 32);     // 1 u32, never reset (mod trick)

    (void)hipFuncSetAttribute((const void*)k1_kernel,
                              hipFuncAttributeMaxDynamicSharedMemorySize,
                              (int)SMEM_BYTES);
    (void)hipFuncSetAttribute((const void*)tail_kernel,
                              hipFuncAttributeMaxDynamicSharedMemorySize,
                              (int)SMEM_BYTES);

    k1_kernel<<<256, NT, SMEM_BYTES, stream>>>(leaf, s1, iem, trans);
    tail_kernel<<<8, NT, SMEM_BYTES, stream>>>(s1, s2, out, iem, trans, cnt);
}